// Round 5
// baseline (464.018 us; speedup 1.0000x reference)
//
#include <hip/hip_runtime.h>
#include <stdint.h>

// Conv: in (32,1,224,224) f32, kernel (64,7,7) f32, pad=3, out (32,64,224,224) f32.
// Implicit GEMM on MFMA (A = im2col patches 16px x K, B = weights^T K x 16 filt,
// K = 7x8 padded = 64 = 2x mfma_f32_16x16x32_f16), verified mapping from round 3.
// NEW: output is staged in LDS (OB) and written to HBM in a separate burst phase:
//   - every store instruction writes 1KB fully contiguous (64 lanes x float4)
//   - per filter, a 2-row x 896B = 1792B run in strictly ascending order
//   - __builtin_nontemporal_store -> streaming writes, full 128B lines, no RFO,
//     no L2 write-back scatter.
// Block = (b, 16-filter group, 2-row strip). LDS 37.3KB -> 4 blocks/CU.

#define H_     224
#define W_     224
#define B_     32
#define F_     64
#define KS_    7
#define ROWS   2
#define LROWS  9               // staged input rows y0-3 .. y0+5 (incl finite ky=7 row)
#define PITCH  232             // input sliding-pair pitch (dwords); 232%32=8
#define FT     452             // OB filter stride (dwords) = 2*224+4; 452%32=4 -> conflict-free b128
#define HW_    (H_ * W_)

typedef _Float16 f16x8 __attribute__((ext_vector_type(8)));
typedef float    f32x4 __attribute__((ext_vector_type(4)));
typedef uint32_t u32x4 __attribute__((ext_vector_type(4)));

__global__ __launch_bounds__(256)
void Conv_58394375356438_kernel(const float* __restrict__ in,
                                const float* __restrict__ wt,
                                float* __restrict__ out)
{
    __shared__ uint32_t P[LROWS * PITCH];   // 8352 B: input sliding half2 pairs
    __shared__ uint32_t OB[16 * FT];        // 28928 B: f32 output stage, [f][row*224+x]

    const int blk   = blockIdx.x;
    const int fg    = blk & 3;                       // 16-filter group
    const int strip = (blk >> 2) % (H_ / ROWS);      // 112 2-row strips
    const int b     = blk / (4 * (H_ / ROWS));
    const int y0    = strip * ROWS;

    const float* __restrict__ inp = in + (size_t)b * HW_;

    // ---- Stage input rows y0-3 .. y0+5 as sliding half pairs: P[lr][i] = (v[i-3], v[i-2]) ----
    for (int idx = threadIdx.x; idx < LROWS * PITCH; idx += 256) {
        const int lr = idx / PITCH;
        const int i  = idx - lr * PITCH;
        const int gy = y0 - 3 + lr;
        const int gx = i - 3;
        float v0 = 0.0f, v1 = 0.0f;
        if (gy >= 0 && gy < H_) {
            const float* __restrict__ row = inp + gy * W_;
            if (gx >= 0 && gx < W_)        v0 = row[gx];
            if (gx >= -1 && gx + 1 < W_)   v1 = row[gx + 1];
        }
        union { _Float16 h[2]; uint32_t u; } pk;
        pk.h[0] = (_Float16)v0;            // RNE, matches passing kernels
        pk.h[1] = (_Float16)v1;
        P[idx] = pk.u;
    }

    const int lane = threadIdx.x & 63;
    const int g    = lane >> 4;        // lane group 0..3
    const int fr   = lane & 15;        // filter-in-tile (B col) == pixel-in-tile (A row)

    // B-operand fragments for this block's 16 filters: ky = kf*4+g, kx 0..7 (7 padded).
    f16x8 wfr[2];
    #pragma unroll
    for (int kf = 0; kf < 2; ++kf) {
        const int ky = kf * 4 + g;
        const float* wrow = wt + (fg * 16 + fr) * (KS_ * KS_) + ky * KS_;
        f16x8 a;
        #pragma unroll
        for (int kx = 0; kx < 8; ++kx) {
            const float w = (ky < KS_ && kx < KS_) ? wrow[kx] : 0.0f;
            a[kx] = (_Float16)w;
        }
        wfr[kf] = a;
    }

    __syncthreads();

    // ---- Compute: wave (rr = wave>>1 row, half = wave&1) handles 7 x-groups ----
    const int wave = threadIdx.x >> 6;
    const int rr   = wave >> 1;          // output row within strip (0..1)
    const int half = wave & 1;           // x-half (xg 0..6 / 7..13)

    const uint32_t* __restrict__ p0 = &P[(rr + g) * PITCH];       // ky = g
    const uint32_t* __restrict__ p1 = &P[(rr + g + 4) * PITCH];   // ky = g+4

    #pragma unroll
    for (int k = 0; k < 7; ++k) {
        const int xg = half * 7 + k;
        const int i0 = xg * 16 + fr;

        u32x4 q0, q1;
        q0[0] = p0[i0];     q0[1] = p0[i0 + 2];
        q0[2] = p0[i0 + 4]; q0[3] = p0[i0 + 6];
        q1[0] = p1[i0];     q1[1] = p1[i0 + 2];
        q1[2] = p1[i0 + 4]; q1[3] = p1[i0 + 6];
        const f16x8 pf0 = __builtin_bit_cast(f16x8, q0);
        const f16x8 pf1 = __builtin_bit_cast(f16x8, q1);

        f32x4 acc = {0.f, 0.f, 0.f, 0.f};
        acc = __builtin_amdgcn_mfma_f32_16x16x32_f16(pf0, wfr[0], acc, 0, 0, 0);
        acc = __builtin_amdgcn_mfma_f32_16x16x32_f16(pf1, wfr[1], acc, 0, 0, 0);

        // D: col=fr=filter, row=4g+j = x offset. OB[f][rr*224 + x], conflict-free quads.
        *reinterpret_cast<f32x4*>(&OB[fr * FT + rr * 224 + xg * 16 + 4 * g]) = acc;
    }

    __syncthreads();

    // ---- Burst: stream OB -> global, ascending addresses, nontemporal ----
    // 16 filters x 112 float4 (2 rows x 896B = 1792B contiguous per filter).
    const size_t plane0 = ((size_t)(b * F_ + fg * 16) * H_ + y0) * W_;
    #pragma unroll
    for (int k = 0; k < 7; ++k) {
        const int i   = k * 256 + threadIdx.x;   // 0..1791
        const int f   = i / 112;
        const int rem = i - f * 112;             // float4 index within filter run
        const f32x4 v = *reinterpret_cast<const f32x4*>(&OB[f * FT + rem * 4]);
        float* __restrict__ dst = out + plane0 + (size_t)f * HW_ + rem * 4;
        __builtin_nontemporal_store(v, reinterpret_cast<f32x4*>(dst));
    }
}

extern "C" void kernel_launch(void* const* d_in, const int* in_sizes, int n_in,
                              void* d_out, int out_size, void* d_ws, size_t ws_size,
                              hipStream_t stream)
{
    const float* in = (const float*)d_in[0];
    const float* wt = (const float*)d_in[1];
    float* out      = (float*)d_out;

    const int grid = B_ * (H_ / ROWS) * (F_ / 16);   // 32*112*4 = 14336 blocks
    Conv_58394375356438_kernel<<<grid, 256, 0, stream>>>(in, wt, out);
}